// Round 10
// baseline (84.435 us; speedup 1.0000x reference)
//
#include <hip/hip_runtime.h>
#include <math.h>

#define NG 1024
#define NC 2
#define HH 224
#define WW 224
#define TILES_X 28
#define TILES_Y 28
#define EPS2D 0.3f
#define ALPHA_MIN (1.0f/255.0f)
#define ALPHA_MAX 0.999f
#define MAXL 512   // per-tile list capacity (exact-support n measured well below)

// Single dispatch, zero cross-block deps. Per 8x8-pixel tile block:
//  1) EXACT prefilter: full prep (quat->cov3d->cov2d->conic) for all 1024
//     gaussians; support ellipse sigma<tau=ln(255*o) with exact diag (a,d)
//     gives the exact tile bbox (superset-free). Candidate records go
//     straight into LDS slots; key = (z_bits<<10)|slot (z>0 -> float bits
//     monotone; slot unique -> strict total order; z bit-ties measure-zero).
//  2) 256-thread in-LDS bitonic sort of the u64 keys — per-tile (z,·) order
//     == global stable depth sort restricted to the tile.
//  3) 4 depth-segment waves composite via permuted wave-uniform LDS reads;
//     partials merged per pixel by (C,T)+(C',T') = (C + T*C', T*T').
__global__ __launch_bounds__(256) void fused_kernel(
        const float* __restrict__ w2cs, const float* __restrict__ Ks,
        const float* __restrict__ xyz, const float* __restrict__ rgb,
        const float* __restrict__ opac, const float* __restrict__ scale,
        const float* __restrict__ rot, float* __restrict__ out) {
    const int cam = blockIdx.z;
    const int TX = blockIdx.x, TY = blockIdx.y;
    const int tid = threadIdx.x;
    const int lane = tid & 63;
    const int wv   = tid >> 6;

    __shared__ unsigned long long keys[MAXL];
    __shared__ float4 sA[MAXL];          // u, v, ia, ib
    __shared__ float4 sB[MAXL];          // id, o, r, g
    __shared__ float  sC[MAXL];          // b
    __shared__ float4 part[4][64];
    __shared__ int scnt;

    if (tid == 0) scnt = 0;
    __syncthreads();

    const float* vm = w2cs + cam*16;
    const float R00 = vm[0],  R01 = vm[1],  R02 = vm[2],  t0 = vm[3];
    const float R10 = vm[4],  R11 = vm[5],  R12 = vm[6],  t1 = vm[7];
    const float R20 = vm[8],  R21 = vm[9],  R22 = vm[10], t2 = vm[11];
    const float* Kc = Ks + cam*9;
    const float fx = Kc[0], cx = Kc[2], fy = Kc[4], cy = Kc[5];
    const float limx = 1.3f * (0.5f * (float)WW / fx);
    const float limy = 1.3f * (0.5f * (float)HH / fy);

    // ---- phase 1: exact prep + prefilter, 4 gaussians per thread ----
    #pragma unroll
    for (int k = 0; k < 4; k++) {
        int g = k*256 + tid;

        float qw = rot[g*4+0], qx = rot[g*4+1], qy = rot[g*4+2], qz = rot[g*4+3];
        float qn = rsqrtf(qw*qw + qx*qx + qy*qy + qz*qz);
        qw *= qn; qx *= qn; qy *= qn; qz *= qn;
        float r00 = 1.f - 2.f*(qy*qy + qz*qz), r01 = 2.f*(qx*qy - qw*qz), r02 = 2.f*(qx*qz + qw*qy);
        float r10 = 2.f*(qx*qy + qw*qz), r11 = 1.f - 2.f*(qx*qx + qz*qz), r12 = 2.f*(qy*qz - qw*qx);
        float r20 = 2.f*(qx*qz - qw*qy), r21 = 2.f*(qy*qz + qw*qx), r22 = 1.f - 2.f*(qx*qx + qy*qy);

        float sx = scale[g*3+0], sy = scale[g*3+1], sz = scale[g*3+2];
        float m00 = r00*sx, m01 = r01*sy, m02 = r02*sz;
        float m10 = r10*sx, m11 = r11*sy, m12 = r12*sz;
        float m20 = r20*sx, m21 = r21*sy, m22 = r22*sz;
        float c00 = m00*m00 + m01*m01 + m02*m02;
        float c01 = m00*m10 + m01*m11 + m02*m12;
        float c02 = m00*m20 + m01*m21 + m02*m22;
        float c11 = m10*m10 + m11*m11 + m12*m12;
        float c12 = m10*m20 + m11*m21 + m12*m22;
        float c22 = m20*m20 + m21*m21 + m22*m22;

        float X = xyz[g*3], Y = xyz[g*3+1], Z = xyz[g*3+2];
        float px = R00*X + R01*Y + R02*Z + t0;
        float py = R10*X + R11*Y + R12*Z + t1;
        float pz = R20*X + R21*Y + R22*Z + t2;
        float rz = 1.f / pz;

        float txc = pz * fminf(fmaxf(px*rz, -limx), limx);
        float tyc = pz * fminf(fmaxf(py*rz, -limy), limy);

        float v00 = R00*c00 + R01*c01 + R02*c02;
        float v01 = R00*c01 + R01*c11 + R02*c12;
        float v02 = R00*c02 + R01*c12 + R02*c22;
        float v10 = R10*c00 + R11*c01 + R12*c02;
        float v11 = R10*c01 + R11*c11 + R12*c12;
        float v12 = R10*c02 + R11*c12 + R12*c22;
        float v20 = R20*c00 + R21*c01 + R22*c02;
        float v21 = R20*c01 + R21*c11 + R22*c12;
        float v22 = R20*c02 + R21*c12 + R22*c22;
        float cc00 = v00*R00 + v01*R01 + v02*R02;
        float cc01 = v00*R10 + v01*R11 + v02*R12;
        float cc02 = v00*R20 + v01*R21 + v02*R22;
        float cc11 = v10*R10 + v11*R11 + v12*R12;
        float cc12 = v10*R20 + v11*R21 + v12*R22;
        float cc22 = v20*R20 + v21*R21 + v22*R22;

        float j00 = fx*rz, j02 = -fx*txc*rz*rz;
        float j11 = fy*rz, j12 = -fy*tyc*rz*rz;
        float a = j00*j00*cc00 + 2.f*j00*j02*cc02 + j02*j02*cc22 + EPS2D;
        float bq = j00*j11*cc01 + j00*j12*cc02 + j02*j11*cc12 + j02*j12*cc22;
        float d = j11*j11*cc11 + 2.f*j11*j12*cc12 + j12*j12*cc22 + EPS2D;
        float det = a*d - bq*bq;

        float o = opac[g];
        float tau = __logf(255.f * o);
        bool cand = (pz > 0.01f) && (pz < 100.f) && (det > 0.f) && (tau > 0.f);

        float u = fx*px*rz + cx;
        float v = fy*py*rz + cy;

        if (cand) {
            // exact support bbox: sigma<tau ellipse, half-extents from conic
            // inverse diag: rx = sqrt(2*tau*a), ry = sqrt(2*tau*d)
            float rx = sqrtf(2.f * tau * a) + 0.01f;
            float ry = sqrtf(2.f * tau * d) + 0.01f;
            int xmin = max((int)ceilf (u - rx - 0.5f), 0);
            int xmax = min((int)floorf(u + rx - 0.5f), WW-1);
            int ymin = max((int)ceilf (v - ry - 0.5f), 0);
            int ymax = min((int)floorf(v + ry - 0.5f), HH-1);
            cand = (xmin <= xmax) && (ymin <= ymax) &&
                   (TX >= (xmin>>3)) && (TX <= (xmax>>3)) &&
                   (TY >= (ymin>>3)) && (TY <= (ymax>>3));
        }

        unsigned long long m = __ballot(cand);
        int cw = __popcll(m);
        if (cw) {
            int basepos = 0;
            if (lane == 0) basepos = atomicAdd(&scnt, cw);
            basepos = __shfl(basepos, 0);
            if (cand) {
                int pos = basepos + __popcll(m & ((1ull << lane) - 1ull));
                if (pos < MAXL) {
                    float idet = 1.f / det;
                    keys[pos] = ((unsigned long long)__float_as_uint(pz) << 10)
                              | (unsigned long long)pos;
                    sA[pos] = make_float4(u, v, d*idet, -bq*idet);
                    sB[pos] = make_float4(a*idet, o, rgb[g*3+0], rgb[g*3+1]);
                    sC[pos] = rgb[g*3+2];
                }
            }
        }
    }
    __syncthreads();
    int n = min(scnt, MAXL);

    // ---- phase 2: bitonic sort of keys (ascending; payload = LDS slot) ----
    int P = 2; while (P < n) P <<= 1;
    for (int i = tid; i < P; i += 256) if (i >= n) keys[i] = ~0ull;
    __syncthreads();
    for (int kk = 2; kk <= P; kk <<= 1) {
        for (int j = kk >> 1; j > 0; j >>= 1) {
            for (int i0 = tid; i0 < P; i0 += 256) {
                int ixj = i0 ^ j;
                if (ixj > i0) {
                    unsigned long long a = keys[i0], b = keys[ixj];
                    bool up = ((i0 & kk) == 0);
                    if ((a > b) == up) { keys[i0] = b; keys[ixj] = a; }
                }
            }
            __syncthreads();
        }
    }

    // ---- phase 3: segmented composite (wave wv = depth segment wv) ----
    const float pxl = (float)(TX*8 + (lane & 7)) + 0.5f;
    const float pyl = (float)(TY*8 + (lane >> 3)) + 0.5f;
    int seglen = (n + 3) >> 2;
    int js = wv * seglen;
    int je = min(n, js + seglen);

    float T = 1.f, cr = 0.f, cg = 0.f, cb = 0.f;
    for (int j = js; j < je; j++) {
        int slot = (int)(keys[j] & 1023ull);   // wave-uniform -> LDS broadcast
        float4 ga = sA[slot];
        float4 gb = sB[slot];
        float  bv = sC[slot];
        float dx = ga.x - pxl;
        float dy = ga.y - pyl;
        float sigma = 0.5f*(ga.z*dx*dx + gb.x*dy*dy) + ga.w*dx*dy;
        float alpha = fminf(gb.y * __expf(-sigma), ALPHA_MAX);
        alpha = (sigma >= 0.f && alpha > ALPHA_MIN) ? alpha : 0.f;
        float w = alpha * T;
        cr += w * gb.z;
        cg += w * gb.w;
        cb += w * bv;
        T  -= alpha * T;
        if (((j - js) & 15) == 15 && __all(T < 1e-4f)) break;
    }

    part[wv][lane] = make_float4(cr, cg, cb, T);
    __syncthreads();

    if (tid < 64) {
        float4 c0 = part[0][lane];
        float Cr = c0.x, Cg = c0.y, Cb = c0.z, Tp = c0.w;
        #pragma unroll
        for (int s = 1; s < 4; s++) {
            float4 cs = part[s][lane];
            Cr += Tp * cs.x;
            Cg += Tp * cs.y;
            Cb += Tp * cs.z;
            Tp *= cs.w;
        }
        int p = (TY*8 + (lane >> 3)) * WW + TX*8 + (lane & 7);
        float* img = out + (size_t)cam * (HH*WW*3) + (size_t)p * 3;
        img[0] = Cr + Tp;           // bg = (1,1,1)
        img[1] = Cg + Tp;
        img[2] = Cb + Tp;
        out[(size_t)NC*HH*WW*3 + (size_t)cam*(HH*WW) + p] = 1.f - Tp;
    }
}

extern "C" void kernel_launch(void* const* d_in, const int* in_sizes, int n_in,
                              void* d_out, int out_size, void* d_ws, size_t ws_size,
                              hipStream_t stream) {
    const float* w2cs  = (const float*)d_in[0];
    const float* Ks    = (const float*)d_in[1];
    const float* xyz   = (const float*)d_in[2];
    const float* rgb   = (const float*)d_in[3];
    const float* opac  = (const float*)d_in[4];
    const float* scale = (const float*)d_in[5];
    const float* rot   = (const float*)d_in[6];
    float* out = (float*)d_out;

    fused_kernel<<<dim3(TILES_X, TILES_Y, NC), 256, 0, stream>>>(
        w2cs, Ks, xyz, rgb, opac, scale, rot, out);
}

// Round 11
// 81.422 us; speedup vs baseline: 1.0370x; 1.0370x over previous
//
#include <hip/hip_runtime.h>
#include <math.h>

#define NG 1024
#define NC 2
#define HH 224
#define WW 224
#define TILES_X 28
#define TILES_Y 28
#define EPS2D 0.3f
#define ALPHA_MIN (1.0f/255.0f)
#define ALPHA_MAX 0.999f
#define MAXL 512   // per-tile list capacity (superset n stays well below)

// Single dispatch, zero cross-block deps. Per 8x8-pixel tile block:
//  1) CHEAP conservative prefilter of all 1024 gaussians: z row + projection
//     + radius bound from lambda_max(Sigma3d) = smax^2 (exact: Sigma3d=R S^2 R^T)
//     and the ACTUAL Jacobian entries (|j02| = fx*|clamp(px*rz)|*rz^... via
//     txc), a strict superset of the exact sigma<tau support. False positives
//     contribute exactly 0 through the alpha>1/255 test.
//  2) compact (z_bits<<10)|gid keys into LDS (shared-atomic slots; key IS the
//     stable (z, gid) order, slot order irrelevant)
//  3) 256-thread bitonic sort — per-tile (z,gid) order == global stable
//     depth sort restricted to the tile
//  4) full prep ONLY for the n listed gaussians (work ~ sum n, not blocks*NG)
//  5) 4 depth-segment waves composite + associative (C,T) merge.
__global__ __launch_bounds__(256) void fused_kernel(
        const float* __restrict__ w2cs, const float* __restrict__ Ks,
        const float* __restrict__ xyz, const float* __restrict__ rgb,
        const float* __restrict__ opac, const float* __restrict__ scale,
        const float* __restrict__ rot, float* __restrict__ out) {
    const int cam = blockIdx.z;
    const int TX = blockIdx.x, TY = blockIdx.y;
    const int tid = threadIdx.x;
    const int lane = tid & 63;
    const int wv   = tid >> 6;

    __shared__ unsigned long long keys[MAXL];
    __shared__ float4 sA[MAXL];          // u, v, ia, ib
    __shared__ float4 sB[MAXL];          // id, o, r, g
    __shared__ float  sC[MAXL];          // b
    __shared__ float4 part[4][64];
    __shared__ int scnt;

    if (tid == 0) scnt = 0;
    __syncthreads();

    const float* vm = w2cs + cam*16;
    const float R00 = vm[0],  R01 = vm[1],  R02 = vm[2],  t0 = vm[3];
    const float R10 = vm[4],  R11 = vm[5],  R12 = vm[6],  t1 = vm[7];
    const float R20 = vm[8],  R21 = vm[9],  R22 = vm[10], t2 = vm[11];
    const float* Kc = Ks + cam*9;
    const float fx = Kc[0], cx = Kc[2], fy = Kc[4], cy = Kc[5];
    const float limx = 1.3f * (0.5f * (float)WW / fx);
    const float limy = 1.3f * (0.5f * (float)HH / fy);

    // ---- phase 1: cheap conservative prefilter, 4 gaussians per thread ----
    #pragma unroll
    for (int k = 0; k < 4; k++) {
        int g = k*256 + tid;
        float X = xyz[g*3], Y = xyz[g*3+1], Z = xyz[g*3+2];
        float pz = R20*X + R21*Y + R22*Z + t2;
        float o  = opac[g];
        float tau = __logf(255.f * o);
        bool cand = (pz > 0.01f) && (pz < 100.f) && (tau > 0.f);
        if (cand) {
            float rz = 1.f / pz;
            float px = R00*X + R01*Y + R02*Z + t0;
            float py = R10*X + R11*Y + R12*Z + t1;
            float u = fx*px*rz + cx;
            float v = fy*py*rz + cy;
            float sx = scale[g*3+0], sy = scale[g*3+1], sz = scale[g*3+2];
            float smax = fmaxf(sx, fmaxf(sy, sz));   // sqrt(lambda_max(Sigma3d)), exact
            // ACTUAL Jacobian entries (txc/tyc are the clamped camera coords)
            float txn = fminf(fmaxf(px*rz, -limx), limx);   // txc = pz*txn
            float tyn = fminf(fmaxf(py*rz, -limy), limy);
            float j00 = fx*rz, j11 = fy*rz;
            float j02 = fx*txn*rz;     // = fx*txc*rz^2 (sign irrelevant, squared)
            float j12 = fy*tyn*rz;
            // a_exact = J Sigma J^T diag <= smax^2 * (row norm)^2 + EPS2D
            float abnd = smax*smax*(j00*j00 + j02*j02) + EPS2D;
            float dbnd = smax*smax*(j11*j11 + j12*j12) + EPS2D;
            float rx = sqrtf(2.f*tau*abnd) + 0.01f;
            float ry = sqrtf(2.f*tau*dbnd) + 0.01f;
            int xmin = max((int)ceilf (u - rx - 0.5f), 0);
            int xmax = min((int)floorf(u + rx - 0.5f), WW-1);
            int ymin = max((int)ceilf (v - ry - 0.5f), 0);
            int ymax = min((int)floorf(v + ry - 0.5f), HH-1);
            cand = (xmin <= xmax) && (ymin <= ymax) &&
                   (TX >= (xmin>>3)) && (TX <= (xmax>>3)) &&
                   (TY >= (ymin>>3)) && (TY <= (ymax>>3));
        }
        unsigned long long m = __ballot(cand);
        int cw = __popcll(m);
        if (cw) {
            int basepos = 0;
            if (lane == 0) basepos = atomicAdd(&scnt, cw);
            basepos = __builtin_amdgcn_readfirstlane(__shfl(basepos, 0));
            if (cand) {
                int pos = basepos + __popcll(m & ((1ull << lane) - 1ull));
                if (pos < MAXL)
                    keys[pos] = ((unsigned long long)__float_as_uint(pz) << 10)
                              | (unsigned long long)g;
            }
        }
    }
    __syncthreads();
    int n = min(scnt, MAXL);

    // ---- phase 2: bitonic sort of keys (ascending (z_bits, gid)) ----
    int P = 2; while (P < n) P <<= 1;
    for (int i = tid; i < P; i += 256) if (i >= n) keys[i] = ~0ull;
    __syncthreads();
    for (int kk = 2; kk <= P; kk <<= 1) {
        for (int j = kk >> 1; j > 0; j >>= 1) {
            for (int i0 = tid; i0 < P; i0 += 256) {
                int ixj = i0 ^ j;
                if (ixj > i0) {
                    unsigned long long a = keys[i0], b = keys[ixj];
                    bool up = ((i0 & kk) == 0);
                    if ((a > b) == up) { keys[i0] = b; keys[ixj] = a; }
                }
            }
            __syncthreads();
        }
    }

    // ---- phase 3: full prep only for listed gaussians, into sorted slots ----
    for (int i = tid; i < n; i += 256) {
        int g = (int)(keys[i] & 1023ull);

        float qw = rot[g*4+0], qx = rot[g*4+1], qy = rot[g*4+2], qz = rot[g*4+3];
        float qn = rsqrtf(qw*qw + qx*qx + qy*qy + qz*qz);
        qw *= qn; qx *= qn; qy *= qn; qz *= qn;
        float r00 = 1.f - 2.f*(qy*qy + qz*qz), r01 = 2.f*(qx*qy - qw*qz), r02 = 2.f*(qx*qz + qw*qy);
        float r10 = 2.f*(qx*qy + qw*qz), r11 = 1.f - 2.f*(qx*qx + qz*qz), r12 = 2.f*(qy*qz - qw*qx);
        float r20 = 2.f*(qx*qz - qw*qy), r21 = 2.f*(qy*qz + qw*qx), r22 = 1.f - 2.f*(qx*qx + qy*qy);

        float sx = scale[g*3+0], sy = scale[g*3+1], sz = scale[g*3+2];
        float m00 = r00*sx, m01 = r01*sy, m02 = r02*sz;
        float m10 = r10*sx, m11 = r11*sy, m12 = r12*sz;
        float m20 = r20*sx, m21 = r21*sy, m22 = r22*sz;
        float c00 = m00*m00 + m01*m01 + m02*m02;
        float c01 = m00*m10 + m01*m11 + m02*m12;
        float c02 = m00*m20 + m01*m21 + m02*m22;
        float c11 = m10*m10 + m11*m11 + m12*m12;
        float c12 = m10*m20 + m11*m21 + m12*m22;
        float c22 = m20*m20 + m21*m21 + m22*m22;

        float X = xyz[g*3], Y = xyz[g*3+1], Z = xyz[g*3+2];
        float px = R00*X + R01*Y + R02*Z + t0;
        float py = R10*X + R11*Y + R12*Z + t1;
        float pz = R20*X + R21*Y + R22*Z + t2;
        float rz = 1.f / pz;

        float txc = pz * fminf(fmaxf(px*rz, -limx), limx);
        float tyc = pz * fminf(fmaxf(py*rz, -limy), limy);

        float v00 = R00*c00 + R01*c01 + R02*c02;
        float v01 = R00*c01 + R01*c11 + R02*c12;
        float v02 = R00*c02 + R01*c12 + R02*c22;
        float v10 = R10*c00 + R11*c01 + R12*c02;
        float v11 = R10*c01 + R11*c11 + R12*c12;
        float v12 = R10*c02 + R11*c12 + R12*c22;
        float v20 = R20*c00 + R21*c01 + R22*c02;
        float v21 = R20*c01 + R21*c11 + R22*c12;
        float v22 = R20*c02 + R21*c12 + R22*c22;
        float cc00 = v00*R00 + v01*R01 + v02*R02;
        float cc01 = v00*R10 + v01*R11 + v02*R12;
        float cc02 = v00*R20 + v01*R21 + v02*R22;
        float cc11 = v10*R10 + v11*R11 + v12*R12;
        float cc12 = v10*R20 + v11*R21 + v12*R22;
        float cc22 = v20*R20 + v21*R21 + v22*R22;

        float j00 = fx*rz, j02 = -fx*txc*rz*rz;
        float j11 = fy*rz, j12 = -fy*tyc*rz*rz;
        float a = j00*j00*cc00 + 2.f*j00*j02*cc02 + j02*j02*cc22 + EPS2D;
        float bq = j00*j11*cc01 + j00*j12*cc02 + j02*j11*cc12 + j02*j12*cc22;
        float d = j11*j11*cc11 + 2.f*j11*j12*cc12 + j12*j12*cc22 + EPS2D;
        float det = a*d - bq*bq;

        bool valid = (pz > 0.01f) && (pz < 100.f) && (det > 0.f);
        float idet = valid ? (1.f / det) : 0.f;
        float ia  = d * idet;
        float ib  = -bq * idet;
        float id_ = a * idet;
        float u = valid ? (fx*px*rz + cx) : 0.f;
        float v = valid ? (fy*py*rz + cy) : 0.f;
        float o = valid ? opac[g] : 0.f;

        sA[i] = make_float4(u, v, ia, ib);
        sB[i] = make_float4(id_, o, rgb[g*3+0], rgb[g*3+1]);
        sC[i] = rgb[g*3+2];
    }
    __syncthreads();

    // ---- phase 4: segmented composite (wave wv = depth segment wv) ----
    const float pxl = (float)(TX*8 + (lane & 7)) + 0.5f;
    const float pyl = (float)(TY*8 + (lane >> 3)) + 0.5f;
    int seglen = (n + 3) >> 2;
    int js = wv * seglen;
    int je = min(n, js + seglen);

    float T = 1.f, cr = 0.f, cg = 0.f, cb = 0.f;
    for (int j = js; j < je; j++) {
        float4 ga = sA[j];        // wave-uniform addr -> LDS broadcast
        float4 gb = sB[j];
        float  bv = sC[j];
        float dx = ga.x - pxl;
        float dy = ga.y - pyl;
        float sigma = 0.5f*(ga.z*dx*dx + gb.x*dy*dy) + ga.w*dx*dy;
        float alpha = fminf(gb.y * __expf(-sigma), ALPHA_MAX);
        alpha = (sigma >= 0.f && alpha > ALPHA_MIN) ? alpha : 0.f;
        float w = alpha * T;
        cr += w * gb.z;
        cg += w * gb.w;
        cb += w * bv;
        T  -= alpha * T;
        if (((j - js) & 15) == 15 && __all(T < 1e-4f)) break;
    }

    part[wv][lane] = make_float4(cr, cg, cb, T);
    __syncthreads();

    if (tid < 64) {
        float4 c0 = part[0][lane];
        float Cr = c0.x, Cg = c0.y, Cb = c0.z, Tp = c0.w;
        #pragma unroll
        for (int s = 1; s < 4; s++) {
            float4 cs = part[s][lane];
            Cr += Tp * cs.x;
            Cg += Tp * cs.y;
            Cb += Tp * cs.z;
            Tp *= cs.w;
        }
        int p = (TY*8 + (lane >> 3)) * WW + TX*8 + (lane & 7);
        float* img = out + (size_t)cam * (HH*WW*3) + (size_t)p * 3;
        img[0] = Cr + Tp;           // bg = (1,1,1)
        img[1] = Cg + Tp;
        img[2] = Cb + Tp;
        out[(size_t)NC*HH*WW*3 + (size_t)cam*(HH*WW) + p] = 1.f - Tp;
    }
}

extern "C" void kernel_launch(void* const* d_in, const int* in_sizes, int n_in,
                              void* d_out, int out_size, void* d_ws, size_t ws_size,
                              hipStream_t stream) {
    const float* w2cs  = (const float*)d_in[0];
    const float* Ks    = (const float*)d_in[1];
    const float* xyz   = (const float*)d_in[2];
    const float* rgb   = (const float*)d_in[3];
    const float* opac  = (const float*)d_in[4];
    const float* scale = (const float*)d_in[5];
    const float* rot   = (const float*)d_in[6];
    float* out = (float*)d_out;

    fused_kernel<<<dim3(TILES_X, TILES_Y, NC), 256, 0, stream>>>(
        w2cs, Ks, xyz, rgb, opac, scale, rot, out);
}